// Round 19
// baseline (16348.618 us; speedup 1.0000x reference)
//
#include <hip/hip_runtime.h>

#define NB 256
#define NT 1024

#define Bv 512
#define Tv 256
#define XDv 128
#define Hv 512
#define DDv 16
#define Pv 32

typedef short s8 __attribute__((ext_vector_type(8)));
typedef float f4 __attribute__((ext_vector_type(4)));
typedef unsigned long long u64;

// ---- ws float offsets ----
#define OFF_KEYP 2048
#define OFF_VALP (OFF_KEYP + 16384)
#define OFF_MF   (OFF_VALP + 16384)
#define OFF_C    (OFF_MF + 16384)
#define OFF_VWG  (OFF_C + 32)
#define OFF_FRG  (OFF_VWG + 32)
// ushort offsets within FRG
#define US_WD   0
#define US_MS   65536
#define US_VP   81920
#define US_WH   98304
#define US_WF   163840
#define US_WHH  180224
#define US_WIH  966656
#define US_END  1409024
#define OFF_H   (OFF_FRG + (US_END/2))   // u32 h double-buffer: 2*512*256 (2 MiB)

// ---- out offsets ----
#define OUT_HS  0
#define OUT_HN  (Bv*Tv*Hv)
#define OUT_XCS (OUT_HN + Bv*Hv)
#define OUT_ZCS (OUT_XCS + Bv*Tv*XDv)

struct Smem {
  unsigned short hA[32*520];    // h rows bf16; overwritten in-place with h' at A4
  unsigned short tA[32*136];    // times(t) bf16
  unsigned short xcA[32*136];   // x_c bf16
  unsigned short inpA[32*296];  // [z_c | m | static | 0pad] bf16
  unsigned short aA[32*40];     // exp(score) bf16
  unsigned short mA[32*136];    // mask(t) bf16
  unsigned short xhS[32*128];   // persistent x_h state bf16
  float xvS[32*132];            // values(t) f32
  float scS[32*34];             // scores + ah at col 32
  float ghS[3*32*33];
  float gxS[3*32*33];
  float hp32[32*32];            // h' f32 own col-tile (GRU carry)
  float al[32], rsm[32], cS[32], vwgS[32];
};

__device__ __forceinline__ unsigned short f2b(float f) {
  union { float f; unsigned int u; } x{f};
  unsigned int r = x.u + 0x7fffu + ((x.u >> 16) & 1u);
  return (unsigned short)(r >> 16);
}
__device__ __forceinline__ float b2f(unsigned short u) {
  union { unsigned int u; float f; } x{(unsigned int)u << 16};
  return x.f;
}
__device__ __forceinline__ float sig_f(float x) { return 1.f / (1.f + __expf(-x)); }
__device__ __forceinline__ float tanh_f(float x) {
  x = fminf(fmaxf(x, -15.f), 15.f);
  float e = __expf(2.f * x);
  return (e - 1.f) / (e + 1.f);
}
__device__ __forceinline__ s8 pack8(const float* p) {
  f4 a = *(const f4*)p; f4 b = *(const f4*)(p + 4);
  s8 r;
  r[0]=(short)f2b(a[0]); r[1]=(short)f2b(a[1]); r[2]=(short)f2b(a[2]); r[3]=(short)f2b(a[3]);
  r[4]=(short)f2b(b[0]); r[5]=(short)f2b(b[1]); r[6]=(short)f2b(b[2]); r[7]=(short)f2b(b[3]);
  return r;
}

// CPol aux: SC0(1) | SC1(16) = 17 -> bypass L1/L2, coherent at L3. Compiler-tracked.
#define CPOL_SC01 17

// ---- init-only grid barrier (fenced; 3 uses) ----
__device__ __forceinline__ void gridbar(unsigned int* bar, unsigned int& lgen, int bid) {
  __syncthreads();
  if (threadIdx.x == 0) {
    __threadfence();
    const unsigned int target = ++lgen;
    unsigned int* grp = bar + (bid >> 4)*16;
    const unsigned int a =
        __hip_atomic_fetch_add(grp, 1u, __ATOMIC_ACQ_REL, __HIP_MEMORY_SCOPE_AGENT);
    if (a == 15u) {
      __hip_atomic_store(grp, 0u, __ATOMIC_RELAXED, __HIP_MEMORY_SCOPE_AGENT);
      const unsigned int r =
          __hip_atomic_fetch_add(bar + 384, 1u, __ATOMIC_ACQ_REL, __HIP_MEMORY_SCOPE_AGENT);
      if (r == 15u) {
        __hip_atomic_store(bar + 384, 0u, __ATOMIC_RELAXED, __HIP_MEMORY_SCOPE_AGENT);
        __hip_atomic_store(bar + 400, target, __ATOMIC_RELEASE, __HIP_MEMORY_SCOPE_AGENT);
      }
    }
    while (__hip_atomic_load(bar + 400, __ATOMIC_RELAXED, __HIP_MEMORY_SCOPE_AGENT) < target)
      __builtin_amdgcn_s_sleep(2);
    __threadfence();
  }
  __syncthreads();
}

// ---- main-loop rg-barrier: fence-free ----
__device__ __forceinline__ void rgbar_nf(unsigned int* bar, unsigned int& lgen, int rg) {
  __syncthreads();
  if (threadIdx.x == 0) {
    const unsigned int target = ++lgen;
    unsigned int* cnt = bar + 512 + rg*64;
    unsigned int* flg = cnt + 32;
    const unsigned int a =
        __hip_atomic_fetch_add(cnt, 1u, __ATOMIC_RELAXED, __HIP_MEMORY_SCOPE_AGENT);
    if (a == 15u) {
      __hip_atomic_store(cnt, 0u, __ATOMIC_RELAXED, __HIP_MEMORY_SCOPE_AGENT);
      asm volatile("s_waitcnt vmcnt(0)" ::: "memory");
      __hip_atomic_store(flg, target, __ATOMIC_RELAXED, __HIP_MEMORY_SCOPE_AGENT);
    } else {
      while (__hip_atomic_load(flg, __ATOMIC_RELAXED, __HIP_MEMORY_SCOPE_AGENT) < target)
        __builtin_amdgcn_s_sleep(2);
    }
  }
  __syncthreads();
}

#define SWZ(DST, NTILES, KT_, EXPR)                                            \
  { const int tot = (NTILES)*(KT_)*512;                                        \
    for (int f = gtid; f < tot; f += NB*NT) {                                  \
      const int e = f & 7, lane_ = (f >> 3) & 63, rem = f >> 9;                \
      const int kt = rem % (KT_), nt = rem / (KT_);                            \
      const int n = nt*16 + (lane_ & 15);                                      \
      const int k = kt*32 + ((lane_ >> 4) & 3)*8 + e;                          \
      (DST)[f] = f2b((EXPR));                                                  \
    } }

#define MFMA(a,b,c) __builtin_amdgcn_mfma_f32_16x16x32_bf16((a),(b),(c),0,0,0)
#define FRAG(P,idx) (*(const s8*)&(P)[((size_t)(idx))*8])
#define NTST(v,p) __builtin_nontemporal_store((v),(p))

__global__
__attribute__((amdgpu_flat_work_group_size(NT, NT), amdgpu_waves_per_eu(4, 4)))
void rits_main(const float* __restrict__ values, const int* __restrict__ lens,
               const float* __restrict__ statc, const float* __restrict__ times,
               const float* __restrict__ masks, const float* __restrict__ prototype,
               const int* __restrict__ protoflag,
               const float* __restrict__ Wd, const float* __restrict__ bd,
               const float* __restrict__ Wh, const float* __restrict__ bh,
               const float* __restrict__ Wf, const float* __restrict__ bf,
               const float* __restrict__ Wq, const float* __restrict__ bq,
               const float* __restrict__ Wk, const float* __restrict__ bk,
               const float* __restrict__ Wv, const float* __restrict__ bv,
               const float* __restrict__ Wg, const float* __restrict__ bg,
               const float* __restrict__ Wih, const float* __restrict__ Whh,
               const float* __restrict__ bih, const float* __restrict__ bhh,
               float* __restrict__ out, float* __restrict__ ws)
{
  const int bid = blockIdx.x, tid = threadIdx.x;
  const int gtid = bid*NT + tid;
  const int wv = tid >> 6, ln = tid & 63;
  const int l15 = ln & 15, l4 = ln >> 4;
  // 2-D XCD tiling (XCD = bid % 8, perf-only): each XCD hosts 4 rg x 8 cg
  const int xcd = bid & 7, sblk = bid >> 3;
  const int rg = (xcd & 3)*4 + (sblk & 3);
  const int cg = (sblk >> 2)*2 + (xcd >> 2);
  const int r0 = rg*32, c0 = cg*32;
  unsigned int* bar = (unsigned int*)ws;
  unsigned int lgenG = 0, lgenR = 0;
  unsigned short* frg = (unsigned short*)(ws + OFF_FRG);
  const unsigned short* wdW  = frg + US_WD;
  const unsigned short* msW  = frg + US_MS;
  const unsigned short* vpW  = frg + US_VP;
  const unsigned short* whW  = frg + US_WH;
  const unsigned short* wfW  = frg + US_WF;
  const unsigned short* whhW = frg + US_WHH;
  const unsigned short* wihW = frg + US_WIH;
  // buffer resource for the h-exchange region (raw, num_records = 2 MiB)
  const __amdgpu_buffer_rsrc_t hsrd =
      __builtin_amdgcn_make_buffer_rsrc((void*)(ws + OFF_H), (short)0,
                                        (int)(2u << 20), 0x00020000);

  __shared__ Smem L;
  const bool proto = protoflag[0] != 0;
  const float scale = 0.17677669529663687f;

  // ============ INIT 1 ============
  for (int o = gtid; o < 2*Pv*Hv; o += NB*NT) {
    const int which = o >> 14, rem = o & 16383;
    const int p = rem >> 9, j = rem & 511;
    const float* W = which ? Wv : Wk;
    const float* bb = which ? bv : bk;
    const float* pr = prototype + p*Hv;
    const float* wr = W + j*Hv;
    float s = bb[j];
    #pragma unroll 4
    for (int k = 0; k < Hv; ++k) s += pr[k]*wr[k];
    ws[(which ? OFF_VALP : OFF_KEYP) + p*Hv + j] = s;
  }
  SWZ(frg + US_WD, 32, 4,  Wd[n*XDv + k])
  SWZ(frg + US_WH, 8, 16,  Wh[n*Hv + k])
  SWZ(frg + US_WF, 8, 4,   (n == k ? 0.f : Wf[n*XDv + k]))
  SWZ(frg + US_WHH, 96, 16,
      Whh[((size_t)(n >> 9)*Hv + (((n >> 5) & 15)*32 + ((n >> 4) & 1)*16 + (n & 15)))*Hv + k])
  SWZ(frg + US_WIH, 96, 9,
      (k < 272 ? Wih[((size_t)(n >> 9)*Hv + (((n >> 5) & 15)*32 + ((n >> 4) & 1)*16 + (n & 15)))*272 + k] : 0.f))
  gridbar(bar, lgenG, bid);

  // ============ INIT 2 ============
  {
    const float* keyp = ws + OFF_KEYP;
    const float* valp = ws + OFF_VALP;
    for (int o = gtid; o < Pv*Hv; o += NB*NT) {
      const int p = o >> 9, kc = o & 511;
      float s = 0.f;
      #pragma unroll 4
      for (int j = 0; j < Hv; ++j) s += keyp[p*Hv + j]*Wq[j*Hv + kc];
      ws[OFF_MF + o] = s;
    }
    if (gtid < 32) {
      float s = 0.f;
      for (int j = 0; j < Hv; ++j) s += bq[j]*keyp[gtid*Hv + j];
      ws[OFF_C + gtid] = s;
    } else if (gtid < 64) {
      const int p = gtid - 32;
      float s = 0.f;
      for (int j = 0; j < Hv; ++j) s += valp[p*Hv + j]*Wg[Hv + j];
      ws[OFF_VWG + p] = s;
    }
  }
  gridbar(bar, lgenG, bid);

  // ============ INIT 3 ============
  SWZ(frg + US_MS, 2, 16, (ws + OFF_MF)[n*Hv + k])
  SWZ(frg + US_VP, 32, 1, (ws + OFF_VALP)[k*Hv + n])
  gridbar(bar, lgenG, bid);

  // ============ block-local LDS init ============
  for (int o = tid; o < 32*128; o += NT) L.xhS[o] = 0;
  if (tid < 32) { L.cS[tid] = ws[OFF_C + tid]; L.vwgS[tid] = ws[OFF_VWG + tid]; }
  for (int o = tid; o < 32*40; o += NT) {
    const int row = o / 40, cc = o % 40;
    L.inpA[row*296 + 256 + cc] =
        (cc < DDv) ? f2b(statc[(r0 + row)*DDv + cc]) : (unsigned short)0;
  }

  // per-thread scalars
  const int w8 = wv & 7;
  const int xcol8 = w8*16 + l15;
  const float bhR = bh[xcol8], bfR = bf[xcol8];
  const int wcg = xcol8 >> 3;           // balanced xcs/zcs writer
  int lensB2[8];
  #pragma unroll
  for (int rt = 0; rt < 2; ++rt)
    #pragma unroll
    for (int i = 0; i < 4; ++i)
      lensB2[rt*4 + i] = lens[r0 + rt*16 + l4*4 + i];
  float wgr[8];
  if (wv >= 8) {
    #pragma unroll
    for (int e = 0; e < 8; ++e) wgr[e] = Wg[ln*8 + e];
  }
  float bdW2[2];
  #pragma unroll
  for (int q = 0; q < 2; ++q) bdW2[q] = bd[(wv*2 + q)*16 + l15];
  const int crow = tid >> 5, cjj = tid & 31;
  float bihR[3], bhhR[3];
  #pragma unroll
  for (int g = 0; g < 3; ++g) { bihR[g] = bih[g*Hv + c0 + cjj]; bhhR[g] = bhh[g*Hv + c0 + cjj]; }
  const int lensG0 = lens[r0 + crow];
  const float bg0 = bg[0];

  // initial input prefetch (t=0)
  float pv[4], pm[4], pt[4];
  #pragma unroll
  for (int i = 0; i < 4; ++i) {
    const int o = i*NT + tid, row = o >> 7, col = o & 127;
    const size_t a = ((size_t)(r0 + row)*Tv + 0)*XDv + col;
    pv[i] = values[a]; pm[i] = masks[a]; pt[i] = times[a];
  }
  __syncthreads();

  // ============ MAIN LOOP ============
  for (int t = 0; t < Tv; ++t) {
    // ---- A1: h exchange loads + PREFETCH A2's ms frags (loop-invariant) ----
    s8 msPre[16];
    if (proto && wv < 2) {
      #pragma unroll
      for (int kt = 0; kt < 16; ++kt)
        msPre[kt] = FRAG(msW, (wv*16 + kt)*64 + ln);
    }
    if (t > 0) {
      const int base = ((t - 1) & 1)*(1 << 20) + r0*1024;   // bytes into wsH
      #pragma unroll
      for (int i = 0; i < 2; ++i) {
        const int e16 = i*NT + tid;                          // 16B-granule index
        auto v = __builtin_amdgcn_raw_buffer_load_b128(hsrd, base + e16*16, 0, CPOL_SC01);
        const int row = e16 >> 6, cp = e16 & 63;
        *(decltype(v)*)&L.hA[row*520 + cp*8] = v;
      }
    } else {
      for (int o = tid; o < 32*128; o += NT) {
        const int row = o >> 7, cp = o & 127;
        ((u64*)&L.hA[row*520])[cp] = 0ull;
      }
    }
    #pragma unroll
    for (int i = 0; i < 4; ++i) {
      const int o = i*NT + tid, row = o >> 7, col = o & 127;
      L.xvS[row*132 + col] = pv[i];
      L.mA[row*136 + col]  = f2b(pm[i]);
      L.tA[row*136 + col]  = f2b(pt[i]);
    }
    {
      const int tn = (t + 1 < Tv) ? t + 1 : t;
      #pragma unroll
      for (int i = 0; i < 4; ++i) {
        const int o = i*NT + tid, row = o >> 7, col = o & 127;
        const size_t a = ((size_t)(r0 + row)*Tv + tn)*XDv + col;
        pv[i] = values[a]; pm[i] = masks[a]; pt[i] = times[a];
      }
    }
    __syncthreads();

    // ---- A2: score (waves 0-1, PRELOADED frags) + ah (waves 8-15) ----
    if (proto) {
      if (wv < 2) {
        const int nt = wv;
        f4 acc0 = {0.f,0.f,0.f,0.f}, acc1 = {0.f,0.f,0.f,0.f};
        #pragma unroll
        for (int kt = 0; kt < 16; ++kt) {
          s8 a0 = *(const s8*)&L.hA[(l15)*520 + kt*32 + l4*8];
          s8 a1 = *(const s8*)&L.hA[(16 + l15)*520 + kt*32 + l4*8];
          acc0 = MFMA(a0, msPre[kt], acc0);
          acc1 = MFMA(a1, msPre[kt], acc1);
        }
        #pragma unroll
        for (int i = 0; i < 4; ++i) {
          L.scS[(l4*4 + i)*34 + nt*16 + l15]      = acc0[i];
          L.scS[(16 + l4*4 + i)*34 + nt*16 + l15] = acc1[i];
        }
      } else if (wv >= 8) {
        #pragma unroll
        for (int rr = 0; rr < 4; ++rr) {
          const int row = (wv - 8)*4 + rr;
          s8 hv8 = *(const s8*)&L.hA[row*520 + ln*8];
          float s = 0.f;
          #pragma unroll
          for (int e = 0; e < 8; ++e) s += b2f((unsigned short)hv8[e]) * wgr[e];
          s += __shfl_xor(s, 1);  s += __shfl_xor(s, 2);  s += __shfl_xor(s, 4);
          s += __shfl_xor(s, 8);  s += __shfl_xor(s, 16); s += __shfl_xor(s, 32);
          if (ln == 0) L.scS[row*34 + 32] = s;
        }
      }
    }
    // PREFETCH A4's wd/vp frags (overlap with A3 softmax)
    s8 wdPre[2][4]; s8 vpPre[2];
    #pragma unroll
    for (int q = 0; q < 2; ++q) {
      const int nt = wv*2 + q;
      #pragma unroll
      for (int kt = 0; kt < 4; ++kt)
        wdPre[q][kt] = FRAG(wdW, (nt*4 + kt)*64 + ln);
      if (proto) vpPre[q] = FRAG(vpW, nt*64 + ln);
    }
    __syncthreads();

    // ---- A3: softmax+alpha, parallel: 16 waves x 2 rows, lane-per-p ----
    if (proto) {
      const int row = wv*2 + (ln >> 5);
      const int p = ln & 31;
      const float sc = (L.scS[row*34 + p] + L.cS[p]) * scale;
      float mx = sc;
      mx = fmaxf(mx, __shfl_xor(mx, 1));  mx = fmaxf(mx, __shfl_xor(mx, 2));
      mx = fmaxf(mx, __shfl_xor(mx, 4));  mx = fmaxf(mx, __shfl_xor(mx, 8));
      mx = fmaxf(mx, __shfl_xor(mx, 16));
      const float e = __expf(sc - mx);
      float sm = e;
      sm += __shfl_xor(sm, 1); sm += __shfl_xor(sm, 2); sm += __shfl_xor(sm, 4);
      sm += __shfl_xor(sm, 8); sm += __shfl_xor(sm, 16);
      float a1 = e * L.vwgS[p];
      a1 += __shfl_xor(a1, 1); a1 += __shfl_xor(a1, 2); a1 += __shfl_xor(a1, 4);
      a1 += __shfl_xor(a1, 8); a1 += __shfl_xor(a1, 16);
      L.aA[row*40 + p] = f2b(e);
      if (p == 0) {
        L.rsm[row] = 1.f / sm;
        L.al[row] = sig_f(L.scS[row*34 + 32] + a1 / sm + bg0);
      }
    }
    __syncthreads();

    // ---- A4: gamma + h1 + blend; PRELOADED wd/vp frags; 2 nt tiles/wave, BOTH rt ----
    {
      s8 ta[2][4]; s8 aa[2];
      #pragma unroll
      for (int rt = 0; rt < 2; ++rt) {
        #pragma unroll
        for (int kt = 0; kt < 4; ++kt)
          ta[rt][kt] = *(const s8*)&L.tA[(rt*16 + l15)*136 + kt*32 + l4*8];
        if (proto) aa[rt] = *(const s8*)&L.aA[(rt*16 + l15)*40 + l4*8];
      }
      #pragma unroll
      for (int q = 0; q < 2; ++q) {
        const int nt = wv*2 + q;
        const int col = nt*16 + l15;
        f4 g2[2] = {{0.f,0.f,0.f,0.f},{0.f,0.f,0.f,0.f}};
        f4 h12[2] = {{0.f,0.f,0.f,0.f},{0.f,0.f,0.f,0.f}};
        #pragma unroll
        for (int kt = 0; kt < 4; ++kt) {
          g2[0] = MFMA(ta[0][kt], wdPre[q][kt], g2[0]);
          g2[1] = MFMA(ta[1][kt], wdPre[q][kt], g2[1]);
        }
        if (proto) {
          h12[0] = MFMA(aa[0], vpPre[q], h12[0]);
          h12[1] = MFMA(aa[1], vpPre[q], h12[1]);
        }
        #pragma unroll
        for (int rt = 0; rt < 2; ++rt) {
          #pragma unroll
          for (int i = 0; i < 4; ++i) {
            const int row = rt*16 + l4*4 + i;
            const float gam = __expf(-fmaxf(g2[rt][i] + bdW2[q], 0.f));
            const float hbf = b2f(L.hA[row*520 + col]);
            float hp;
            if (proto) {
              const float av = L.al[row];
              hp = (av*hbf + (1.f - av)*h12[rt][i]*L.rsm[row]) * gam;
            } else hp = hbf * gam;
            L.hA[row*520 + col] = f2b(hp);
            const unsigned cc = (unsigned)(col - c0);
            if (cc < 32u) L.hp32[row*32 + cc] = hp;
          }
        }
      }
    }
    __syncthreads();

    // ---- B2s: x_h (waves 0-7, both rt) + gh (waves 8-13, both rt) ----
    if (wv < 8) {
      f4 accX[2] = {{0.f,0.f,0.f,0.f},{0.f,0.f,0.f,0.f}};
      #pragma unroll
      for (int kt = 0; kt < 16; ++kt) {
        s8 b  = FRAG(whW, (wv*16 + kt)*64 + ln);
        s8 a0 = *(const s8*)&L.hA[(l15)*520 + kt*32 + l4*8];
        s8 a1 = *(const s8*)&L.hA[(16 + l15)*520 + kt*32 + l4*8];
        accX[0] = MFMA(a0, b, accX[0]);
        accX[1] = MFMA(a1, b, accX[1]);
      }
      #pragma unroll
      for (int rt = 0; rt < 2; ++rt) {
        #pragma unroll
        for (int i = 0; i < 4; ++i) {
          const int row = rt*16 + l4*4 + i;
          const int b = r0 + row;
          float xh = accX[rt][i] + bhR;
          if (t < lensB2[rt*4 + i]) L.xhS[row*128 + xcol8] = f2b(xh);
          else                      xh = b2f(L.xhS[row*128 + xcol8]);
          const float xv = L.xvS[row*132 + xcol8], mv = b2f(L.mA[row*136 + xcol8]);
          const float xc = mv*xv + (1.f - mv)*xh;
          if (wcg == cg) NTST(xc, &out[OUT_XCS + ((size_t)b*Tv + t)*XDv + xcol8]);
          L.xcA[row*136 + xcol8] = f2b(xc);
        }
      }
    } else if (wv < 14) {
      const int j = wv - 8, g = j >> 1, hf = j & 1;
      const int ntG = g*32 + cg*2 + hf;
      const int cLoc = hf*16 + l15;
      f4 accG[2] = {{0.f,0.f,0.f,0.f},{0.f,0.f,0.f,0.f}};
      #pragma unroll
      for (int kt = 0; kt < 16; ++kt) {
        s8 b  = FRAG(whhW, (ntG*16 + kt)*64 + ln);
        s8 a0 = *(const s8*)&L.hA[(l15)*520 + kt*32 + l4*8];
        s8 a1 = *(const s8*)&L.hA[(16 + l15)*520 + kt*32 + l4*8];
        accG[0] = MFMA(a0, b, accG[0]);
        accG[1] = MFMA(a1, b, accG[1]);
      }
      #pragma unroll
      for (int rt = 0; rt < 2; ++rt)
        #pragma unroll
        for (int i = 0; i < 4; ++i)
          L.ghS[g*1056 + (rt*16 + l4*4 + i)*33 + cLoc] = accG[rt][i];
    }
    __syncthreads();

    // ---- B3s: z_h + z_c (16 waves, single rt) ----
    {
      const int wrt = wv >> 3;
      f4 acc = {0.f,0.f,0.f,0.f};
      #pragma unroll
      for (int kt = 0; kt < 4; ++kt) {
        s8 a = *(const s8*)&L.xcA[(wrt*16 + l15)*136 + kt*32 + l4*8];
        acc = MFMA(a, FRAG(wfW, (w8*4 + kt)*64 + ln), acc);
      }
      #pragma unroll
      for (int i = 0; i < 4; ++i) {
        const int row = wrt*16 + l4*4 + i;
        const float xv = L.xvS[row*132 + xcol8], mv = b2f(L.mA[row*136 + xcol8]);
        const float zc = mv*xv + (1.f - mv)*(acc[i] + bfR);
        if (wcg == cg) NTST(zc, &out[OUT_ZCS + ((size_t)(r0 + row)*Tv + t)*XDv + xcol8]);
        L.inpA[row*296 + xcol8]       = f2b(zc);
        L.inpA[row*296 + 128 + xcol8] = f2b(mv);
      }
    }
    __syncthreads();

    // ---- B4s: gx on waves 0-11 ----
    if (wv < 12) {
      const int g = wv >> 2, sub = wv & 3;
      const int hf = sub >> 1, rt = sub & 1;
      const int ntG = g*32 + cg*2 + hf;
      const int cLoc = hf*16 + l15;
      f4 acc = {0.f,0.f,0.f,0.f};
      #pragma unroll
      for (int kt = 0; kt < 9; ++kt) {
        s8 a = *(const s8*)&L.inpA[(rt*16 + l15)*296 + kt*32 + l4*8];
        acc = MFMA(a, FRAG(wihW, (ntG*9 + kt)*64 + ln), acc);
      }
      #pragma unroll
      for (int i = 0; i < 4; ++i)
        L.gxS[g*1056 + (rt*16 + l4*4 + i)*33 + cLoc] = acc[i];
    }
    __syncthreads();

    // ---- B5s: GRU (1 cell/thread) -> out + h exchange via sc0|sc1 buffer store ----
    {
      const int row = crow;
      const int b = r0 + row, jc = c0 + cjj;
      const float xr = L.gxS[row*33 + cjj]        + bihR[0];
      const float xz = L.gxS[1056 + row*33 + cjj] + bihR[1];
      const float xn = L.gxS[2112 + row*33 + cjj] + bihR[2];
      const float hr = L.ghS[row*33 + cjj]        + bhhR[0];
      const float hz = L.ghS[1056 + row*33 + cjj] + bhhR[1];
      const float hn = L.ghS[2112 + row*33 + cjj] + bhhR[2];
      const float r = sig_f(xr + hr), z = sig_f(xz + hz);
      const float n = tanh_f(xn + r*hn);
      const float hpv = L.hp32[row*32 + cjj];
      const float hfv = (t < lensG0) ? ((1.f - z)*n + z*hpv) : hpv;
      const float partner = __shfl_xor(hfv, 1);
      if ((cjj & 1) == 0) {
        const unsigned int pk = (unsigned int)f2b(hfv) | ((unsigned int)f2b(partner) << 16);
        const int voff = (t & 1)*(1 << 20) + (b*256 + cg*16 + (cjj >> 1))*4;
        __builtin_amdgcn_raw_buffer_store_b32(pk, hsrd, voff, 0, CPOL_SC01);
      }
      NTST(hfv, &out[OUT_HS + ((size_t)b*Tv + t)*Hv + jc]);
      if (t == Tv - 1) NTST(hfv, &out[OUT_HN + (size_t)b*Hv + jc]);
    }
    rgbar_nf(bar, lgenR, rg);
  }
}

extern "C" void kernel_launch(void* const* d_in, const int* in_sizes, int n_in,
                              void* d_out, int out_size, void* d_ws, size_t ws_size,
                              hipStream_t stream) {
  (void)in_sizes; (void)n_in; (void)out_size; (void)ws_size;
  hipMemsetAsync(d_ws, 0, 8192, stream);
  rits_main<<<NB, NT, 0, stream>>>(
      (const float*)d_in[0],  (const int*)d_in[1],   (const float*)d_in[2],
      (const float*)d_in[3],  (const float*)d_in[4], (const float*)d_in[5],
      (const int*)d_in[6],
      (const float*)d_in[7],  (const float*)d_in[8],
      (const float*)d_in[9],  (const float*)d_in[10],
      (const float*)d_in[11], (const float*)d_in[12],
      (const float*)d_in[13], (const float*)d_in[14],
      (const float*)d_in[15], (const float*)d_in[16],
      (const float*)d_in[17], (const float*)d_in[18],
      (const float*)d_in[19], (const float*)d_in[20],
      (const float*)d_in[21], (const float*)d_in[22],
      (const float*)d_in[23], (const float*)d_in[24],
      (float*)d_out, (float*)d_ws);
}

// Round 20
// 13239.101 us; speedup vs baseline: 1.2349x; 1.2349x over previous
//
#include <hip/hip_runtime.h>

#define NB 256
#define NT 1024

#define Bv 512
#define Tv 256
#define XDv 128
#define Hv 512
#define DDv 16
#define Pv 32

typedef short s8 __attribute__((ext_vector_type(8)));
typedef float f4 __attribute__((ext_vector_type(4)));
typedef unsigned long long u64;

// ---- ws float offsets ----
#define OFF_KEYP 2048
#define OFF_VALP (OFF_KEYP + 16384)
#define OFF_MF   (OFF_VALP + 16384)
#define OFF_C    (OFF_MF + 16384)
#define OFF_VWG  (OFF_C + 32)
#define OFF_FRG  (OFF_VWG + 32)
// ushort offsets within FRG
#define US_WD   0
#define US_MS   65536
#define US_VP   81920
#define US_WH   98304
#define US_WF   163840
#define US_WHH  180224
#define US_WIH  966656
#define US_END  1409024
#define OFF_H   (OFF_FRG + (US_END/2))   // u32 h double-buffer: 2*512*256 (2 MiB)

// ---- out offsets ----
#define OUT_HS  0
#define OUT_HN  (Bv*Tv*Hv)
#define OUT_XCS (OUT_HN + Bv*Hv)
#define OUT_ZCS (OUT_XCS + Bv*Tv*XDv)

struct Smem {
  unsigned short hA[32*520];    // h rows bf16; overwritten in-place with h' at A4
  unsigned short tA[32*136];    // times(t) bf16
  unsigned short xcA[32*136];   // x_c bf16
  unsigned short inpA[32*296];  // [z_c | m | static | 0pad] bf16
  unsigned short aA[32*40];     // exp(score) bf16
  unsigned short mA[32*136];    // mask(t) bf16
  unsigned short xhS[32*128];   // persistent x_h state bf16
  float xvS[32*132];            // values(t) f32
  float scS[32*34];             // scores + ah at col 32
  float ghS[3*32*33];
  float gxS[3*32*33];
  float hp32[32*32];            // h' f32 own col-tile (GRU carry)
  float al[32], rsm[32], cS[32], vwgS[32];
};

__device__ __forceinline__ unsigned short f2b(float f) {
  union { float f; unsigned int u; } x{f};
  unsigned int r = x.u + 0x7fffu + ((x.u >> 16) & 1u);
  return (unsigned short)(r >> 16);
}
__device__ __forceinline__ float b2f(unsigned short u) {
  union { unsigned int u; float f; } x{(unsigned int)u << 16};
  return x.f;
}
__device__ __forceinline__ float sig_f(float x) { return 1.f / (1.f + __expf(-x)); }
__device__ __forceinline__ float tanh_f(float x) {
  x = fminf(fmaxf(x, -15.f), 15.f);
  float e = __expf(2.f * x);
  return (e - 1.f) / (e + 1.f);
}
__device__ __forceinline__ s8 pack8(const float* p) {
  f4 a = *(const f4*)p; f4 b = *(const f4*)(p + 4);
  s8 r;
  r[0]=(short)f2b(a[0]); r[1]=(short)f2b(a[1]); r[2]=(short)f2b(a[2]); r[3]=(short)f2b(a[3]);
  r[4]=(short)f2b(b[0]); r[5]=(short)f2b(b[1]); r[6]=(short)f2b(b[2]); r[7]=(short)f2b(b[3]);
  return r;
}

// CPol aux: SC0(1) | SC1(16) = 17 -> bypass L1/L2, coherent at L3. Compiler-tracked.
#define CPOL_SC01 17

// ---- init-only grid barrier (fenced; 3 uses) ----
__device__ __forceinline__ void gridbar(unsigned int* bar, unsigned int& lgen, int bid) {
  __syncthreads();
  if (threadIdx.x == 0) {
    __threadfence();
    const unsigned int target = ++lgen;
    unsigned int* grp = bar + (bid >> 4)*16;
    const unsigned int a =
        __hip_atomic_fetch_add(grp, 1u, __ATOMIC_ACQ_REL, __HIP_MEMORY_SCOPE_AGENT);
    if (a == 15u) {
      __hip_atomic_store(grp, 0u, __ATOMIC_RELAXED, __HIP_MEMORY_SCOPE_AGENT);
      const unsigned int r =
          __hip_atomic_fetch_add(bar + 384, 1u, __ATOMIC_ACQ_REL, __HIP_MEMORY_SCOPE_AGENT);
      if (r == 15u) {
        __hip_atomic_store(bar + 384, 0u, __ATOMIC_RELAXED, __HIP_MEMORY_SCOPE_AGENT);
        __hip_atomic_store(bar + 400, target, __ATOMIC_RELEASE, __HIP_MEMORY_SCOPE_AGENT);
      }
    }
    while (__hip_atomic_load(bar + 400, __ATOMIC_RELAXED, __HIP_MEMORY_SCOPE_AGENT) < target)
      __builtin_amdgcn_s_sleep(2);
    __threadfence();
  }
  __syncthreads();
}

// ---- main-loop rg-barrier: fence-free ----
__device__ __forceinline__ void rgbar_nf(unsigned int* bar, unsigned int& lgen, int rg) {
  __syncthreads();
  if (threadIdx.x == 0) {
    const unsigned int target = ++lgen;
    unsigned int* cnt = bar + 512 + rg*64;
    unsigned int* flg = cnt + 32;
    const unsigned int a =
        __hip_atomic_fetch_add(cnt, 1u, __ATOMIC_RELAXED, __HIP_MEMORY_SCOPE_AGENT);
    if (a == 15u) {
      __hip_atomic_store(cnt, 0u, __ATOMIC_RELAXED, __HIP_MEMORY_SCOPE_AGENT);
      asm volatile("s_waitcnt vmcnt(0)" ::: "memory");
      __hip_atomic_store(flg, target, __ATOMIC_RELAXED, __HIP_MEMORY_SCOPE_AGENT);
    } else {
      while (__hip_atomic_load(flg, __ATOMIC_RELAXED, __HIP_MEMORY_SCOPE_AGENT) < target)
        __builtin_amdgcn_s_sleep(2);
    }
  }
  __syncthreads();
}

#define SWZ(DST, NTILES, KT_, EXPR)                                            \
  { const int tot = (NTILES)*(KT_)*512;                                        \
    for (int f = gtid; f < tot; f += NB*NT) {                                  \
      const int e = f & 7, lane_ = (f >> 3) & 63, rem = f >> 9;                \
      const int kt = rem % (KT_), nt = rem / (KT_);                            \
      const int n = nt*16 + (lane_ & 15);                                      \
      const int k = kt*32 + ((lane_ >> 4) & 3)*8 + e;                          \
      (DST)[f] = f2b((EXPR));                                                  \
    } }

#define MFMA(a,b,c) __builtin_amdgcn_mfma_f32_16x16x32_bf16((a),(b),(c),0,0,0)
#define FRAG(P,idx) (*(const s8*)&(P)[((size_t)(idx))*8])
#define NTST(v,p) __builtin_nontemporal_store((v),(p))

__global__ __launch_bounds__(NT, 4)
void rits_main(const float* __restrict__ values, const int* __restrict__ lens,
               const float* __restrict__ statc, const float* __restrict__ times,
               const float* __restrict__ masks, const float* __restrict__ prototype,
               const int* __restrict__ protoflag,
               const float* __restrict__ Wd, const float* __restrict__ bd,
               const float* __restrict__ Wh, const float* __restrict__ bh,
               const float* __restrict__ Wf, const float* __restrict__ bf,
               const float* __restrict__ Wq, const float* __restrict__ bq,
               const float* __restrict__ Wk, const float* __restrict__ bk,
               const float* __restrict__ Wv, const float* __restrict__ bv,
               const float* __restrict__ Wg, const float* __restrict__ bg,
               const float* __restrict__ Wih, const float* __restrict__ Whh,
               const float* __restrict__ bih, const float* __restrict__ bhh,
               float* __restrict__ out, float* __restrict__ ws)
{
  const int bid = blockIdx.x, tid = threadIdx.x;
  const int gtid = bid*NT + tid;
  const int wv = tid >> 6, ln = tid & 63;
  const int l15 = ln & 15, l4 = ln >> 4;
  // 2-D XCD tiling (XCD = bid % 8, perf-only): each XCD hosts 4 rg x 8 cg
  const int xcd = bid & 7, sblk = bid >> 3;
  const int rg = (xcd & 3)*4 + (sblk & 3);
  const int cg = (sblk >> 2)*2 + (xcd >> 2);
  const int r0 = rg*32, c0 = cg*32;
  unsigned int* bar = (unsigned int*)ws;
  unsigned int lgenG = 0, lgenR = 0;
  unsigned short* frg = (unsigned short*)(ws + OFF_FRG);
  const unsigned short* wdW  = frg + US_WD;
  const unsigned short* msW  = frg + US_MS;
  const unsigned short* vpW  = frg + US_VP;
  const unsigned short* whW  = frg + US_WH;
  const unsigned short* wfW  = frg + US_WF;
  const unsigned short* whhW = frg + US_WHH;
  const unsigned short* wihW = frg + US_WIH;
  // buffer resource for the h-exchange region (raw, num_records = 2 MiB)
  const __amdgpu_buffer_rsrc_t hsrd =
      __builtin_amdgcn_make_buffer_rsrc((void*)(ws + OFF_H), (short)0,
                                        (int)(2u << 20), 0x00020000);

  __shared__ Smem L;
  const bool proto = protoflag[0] != 0;
  const float scale = 0.17677669529663687f;

  // ============ INIT 1 ============
  for (int o = gtid; o < 2*Pv*Hv; o += NB*NT) {
    const int which = o >> 14, rem = o & 16383;
    const int p = rem >> 9, j = rem & 511;
    const float* W = which ? Wv : Wk;
    const float* bb = which ? bv : bk;
    const float* pr = prototype + p*Hv;
    const float* wr = W + j*Hv;
    float s = bb[j];
    #pragma unroll 4
    for (int k = 0; k < Hv; ++k) s += pr[k]*wr[k];
    ws[(which ? OFF_VALP : OFF_KEYP) + p*Hv + j] = s;
  }
  SWZ(frg + US_WD, 32, 4,  Wd[n*XDv + k])
  SWZ(frg + US_WH, 8, 16,  Wh[n*Hv + k])
  SWZ(frg + US_WF, 8, 4,   (n == k ? 0.f : Wf[n*XDv + k]))
  SWZ(frg + US_WHH, 96, 16,
      Whh[((size_t)(n >> 9)*Hv + (((n >> 5) & 15)*32 + ((n >> 4) & 1)*16 + (n & 15)))*Hv + k])
  SWZ(frg + US_WIH, 96, 9,
      (k < 272 ? Wih[((size_t)(n >> 9)*Hv + (((n >> 5) & 15)*32 + ((n >> 4) & 1)*16 + (n & 15)))*272 + k] : 0.f))
  gridbar(bar, lgenG, bid);

  // ============ INIT 2 ============
  {
    const float* keyp = ws + OFF_KEYP;
    const float* valp = ws + OFF_VALP;
    for (int o = gtid; o < Pv*Hv; o += NB*NT) {
      const int p = o >> 9, kc = o & 511;
      float s = 0.f;
      #pragma unroll 4
      for (int j = 0; j < Hv; ++j) s += keyp[p*Hv + j]*Wq[j*Hv + kc];
      ws[OFF_MF + o] = s;
    }
    if (gtid < 32) {
      float s = 0.f;
      for (int j = 0; j < Hv; ++j) s += bq[j]*keyp[gtid*Hv + j];
      ws[OFF_C + gtid] = s;
    } else if (gtid < 64) {
      const int p = gtid - 32;
      float s = 0.f;
      for (int j = 0; j < Hv; ++j) s += valp[p*Hv + j]*Wg[Hv + j];
      ws[OFF_VWG + p] = s;
    }
  }
  gridbar(bar, lgenG, bid);

  // ============ INIT 3 ============
  SWZ(frg + US_MS, 2, 16, (ws + OFF_MF)[n*Hv + k])
  SWZ(frg + US_VP, 32, 1, (ws + OFF_VALP)[k*Hv + n])
  gridbar(bar, lgenG, bid);

  // ============ block-local LDS init ============
  for (int o = tid; o < 32*128; o += NT) L.xhS[o] = 0;
  if (tid < 32) { L.cS[tid] = ws[OFF_C + tid]; L.vwgS[tid] = ws[OFF_VWG + tid]; }
  for (int o = tid; o < 32*40; o += NT) {
    const int row = o / 40, cc = o % 40;
    L.inpA[row*296 + 256 + cc] =
        (cc < DDv) ? f2b(statc[(r0 + row)*DDv + cc]) : (unsigned short)0;
  }

  // per-thread scalars
  const int w8 = wv & 7;
  const int xcol8 = w8*16 + l15;
  const float bhR = bh[xcol8], bfR = bf[xcol8];
  const int wcg = xcol8 >> 3;           // balanced xcs/zcs writer
  int lensB2[8];
  #pragma unroll
  for (int rt = 0; rt < 2; ++rt)
    #pragma unroll
    for (int i = 0; i < 4; ++i)
      lensB2[rt*4 + i] = lens[r0 + rt*16 + l4*4 + i];
  float wgr[8];
  if (wv >= 8) {
    #pragma unroll
    for (int e = 0; e < 8; ++e) wgr[e] = Wg[ln*8 + e];
  }
  float bdW2[2];
  #pragma unroll
  for (int q = 0; q < 2; ++q) bdW2[q] = bd[(wv*2 + q)*16 + l15];
  const int crow = tid >> 5, cjj = tid & 31;
  float bihR[3], bhhR[3];
  #pragma unroll
  for (int g = 0; g < 3; ++g) { bihR[g] = bih[g*Hv + c0 + cjj]; bhhR[g] = bhh[g*Hv + c0 + cjj]; }
  const int lensG0 = lens[r0 + crow];
  const float bg0 = bg[0];

  // initial input prefetch (t=0)
  float pv[4], pm[4], pt[4];
  #pragma unroll
  for (int i = 0; i < 4; ++i) {
    const int o = i*NT + tid, row = o >> 7, col = o & 127;
    const size_t a = ((size_t)(r0 + row)*Tv + 0)*XDv + col;
    pv[i] = values[a]; pm[i] = masks[a]; pt[i] = times[a];
  }
  __syncthreads();

  // ============ MAIN LOOP ============
  for (int t = 0; t < Tv; ++t) {
    // ---- A1: h exchange via WIDE sc0|sc1 buffer loads; inputs; prefetch t+1 ----
    if (t > 0) {
      const int base = ((t - 1) & 1)*(1 << 20) + r0*1024;   // bytes into wsH
      #pragma unroll
      for (int i = 0; i < 2; ++i) {
        const int e16 = i*NT + tid;                          // 16B-granule index
        auto v = __builtin_amdgcn_raw_buffer_load_b128(hsrd, base + e16*16, 0, CPOL_SC01);
        const int row = e16 >> 6, cp = e16 & 63;
        *(decltype(v)*)&L.hA[row*520 + cp*8] = v;
      }
    } else {
      for (int o = tid; o < 32*128; o += NT) {
        const int row = o >> 7, cp = o & 127;
        ((u64*)&L.hA[row*520])[cp] = 0ull;
      }
    }
    #pragma unroll
    for (int i = 0; i < 4; ++i) {
      const int o = i*NT + tid, row = o >> 7, col = o & 127;
      L.xvS[row*132 + col] = pv[i];
      L.mA[row*136 + col]  = f2b(pm[i]);
      L.tA[row*136 + col]  = f2b(pt[i]);
    }
    {
      const int tn = (t + 1 < Tv) ? t + 1 : t;
      #pragma unroll
      for (int i = 0; i < 4; ++i) {
        const int o = i*NT + tid, row = o >> 7, col = o & 127;
        const size_t a = ((size_t)(r0 + row)*Tv + tn)*XDv + col;
        pv[i] = values[a]; pm[i] = masks[a]; pt[i] = times[a];
      }
    }
    __syncthreads();

    // ---- A2: score (waves 0-1, both rt) + ah (waves 8-15) ----
    if (proto) {
      if (wv < 2) {
        const int nt = wv;
        f4 acc0 = {0.f,0.f,0.f,0.f}, acc1 = {0.f,0.f,0.f,0.f};
        #pragma unroll
        for (int kt = 0; kt < 16; ++kt) {
          s8 b  = FRAG(msW, (nt*16 + kt)*64 + ln);
          s8 a0 = *(const s8*)&L.hA[(l15)*520 + kt*32 + l4*8];
          s8 a1 = *(const s8*)&L.hA[(16 + l15)*520 + kt*32 + l4*8];
          acc0 = MFMA(a0, b, acc0);
          acc1 = MFMA(a1, b, acc1);
        }
        #pragma unroll
        for (int i = 0; i < 4; ++i) {
          L.scS[(l4*4 + i)*34 + nt*16 + l15]      = acc0[i];
          L.scS[(16 + l4*4 + i)*34 + nt*16 + l15] = acc1[i];
        }
      } else if (wv >= 8) {
        #pragma unroll
        for (int rr = 0; rr < 4; ++rr) {
          const int row = (wv - 8)*4 + rr;
          s8 hv8 = *(const s8*)&L.hA[row*520 + ln*8];
          float s = 0.f;
          #pragma unroll
          for (int e = 0; e < 8; ++e) s += b2f((unsigned short)hv8[e]) * wgr[e];
          s += __shfl_xor(s, 1);  s += __shfl_xor(s, 2);  s += __shfl_xor(s, 4);
          s += __shfl_xor(s, 8);  s += __shfl_xor(s, 16); s += __shfl_xor(s, 32);
          if (ln == 0) L.scS[row*34 + 32] = s;
        }
      }
    }
    __syncthreads();

    // ---- A3: softmax+alpha, parallel: 16 waves x 2 rows, lane-per-p ----
    if (proto) {
      const int row = wv*2 + (ln >> 5);
      const int p = ln & 31;
      const float sc = (L.scS[row*34 + p] + L.cS[p]) * scale;
      float mx = sc;
      mx = fmaxf(mx, __shfl_xor(mx, 1));  mx = fmaxf(mx, __shfl_xor(mx, 2));
      mx = fmaxf(mx, __shfl_xor(mx, 4));  mx = fmaxf(mx, __shfl_xor(mx, 8));
      mx = fmaxf(mx, __shfl_xor(mx, 16));
      const float e = __expf(sc - mx);
      float sm = e;
      sm += __shfl_xor(sm, 1); sm += __shfl_xor(sm, 2); sm += __shfl_xor(sm, 4);
      sm += __shfl_xor(sm, 8); sm += __shfl_xor(sm, 16);
      float a1 = e * L.vwgS[p];
      a1 += __shfl_xor(a1, 1); a1 += __shfl_xor(a1, 2); a1 += __shfl_xor(a1, 4);
      a1 += __shfl_xor(a1, 8); a1 += __shfl_xor(a1, 16);
      L.aA[row*40 + p] = f2b(e);
      if (p == 0) {
        L.rsm[row] = 1.f / sm;
        L.al[row] = sig_f(L.scS[row*34 + 32] + a1 / sm + bg0);
      }
    }
    __syncthreads();

    // ---- A4: gamma + h1 + blend; 2 nt tiles/wave, BOTH rt ----
    {
      s8 ta[2][4]; s8 aa[2];
      #pragma unroll
      for (int rt = 0; rt < 2; ++rt) {
        #pragma unroll
        for (int kt = 0; kt < 4; ++kt)
          ta[rt][kt] = *(const s8*)&L.tA[(rt*16 + l15)*136 + kt*32 + l4*8];
        if (proto) aa[rt] = *(const s8*)&L.aA[(rt*16 + l15)*40 + l4*8];
      }
      #pragma unroll
      for (int q = 0; q < 2; ++q) {
        const int nt = wv*2 + q;
        const int col = nt*16 + l15;
        f4 g2[2] = {{0.f,0.f,0.f,0.f},{0.f,0.f,0.f,0.f}};
        f4 h12[2] = {{0.f,0.f,0.f,0.f},{0.f,0.f,0.f,0.f}};
        #pragma unroll
        for (int kt = 0; kt < 4; ++kt) {
          s8 b = FRAG(wdW, (nt*4 + kt)*64 + ln);
          g2[0] = MFMA(ta[0][kt], b, g2[0]);
          g2[1] = MFMA(ta[1][kt], b, g2[1]);
        }
        if (proto) {
          s8 b = FRAG(vpW, nt*64 + ln);
          h12[0] = MFMA(aa[0], b, h12[0]);
          h12[1] = MFMA(aa[1], b, h12[1]);
        }
        #pragma unroll
        for (int rt = 0; rt < 2; ++rt) {
          #pragma unroll
          for (int i = 0; i < 4; ++i) {
            const int row = rt*16 + l4*4 + i;
            const float gam = __expf(-fmaxf(g2[rt][i] + bdW2[q], 0.f));
            const float hbf = b2f(L.hA[row*520 + col]);
            float hp;
            if (proto) {
              const float av = L.al[row];
              hp = (av*hbf + (1.f - av)*h12[rt][i]*L.rsm[row]) * gam;
            } else hp = hbf * gam;
            L.hA[row*520 + col] = f2b(hp);
            const unsigned cc = (unsigned)(col - c0);
            if (cc < 32u) L.hp32[row*32 + cc] = hp;
          }
        }
      }
    }
    __syncthreads();

    // ---- B2s: x_h (waves 0-7, both rt) + gh (waves 8-13, both rt) ----
    if (wv < 8) {
      f4 accX[2] = {{0.f,0.f,0.f,0.f},{0.f,0.f,0.f,0.f}};
      #pragma unroll
      for (int kt = 0; kt < 16; ++kt) {
        s8 b  = FRAG(whW, (wv*16 + kt)*64 + ln);
        s8 a0 = *(const s8*)&L.hA[(l15)*520 + kt*32 + l4*8];
        s8 a1 = *(const s8*)&L.hA[(16 + l15)*520 + kt*32 + l4*8];
        accX[0] = MFMA(a0, b, accX[0]);
        accX[1] = MFMA(a1, b, accX[1]);
      }
      #pragma unroll
      for (int rt = 0; rt < 2; ++rt) {
        #pragma unroll
        for (int i = 0; i < 4; ++i) {
          const int row = rt*16 + l4*4 + i;
          const int b = r0 + row;
          float xh = accX[rt][i] + bhR;
          if (t < lensB2[rt*4 + i]) L.xhS[row*128 + xcol8] = f2b(xh);
          else                      xh = b2f(L.xhS[row*128 + xcol8]);
          const float xv = L.xvS[row*132 + xcol8], mv = b2f(L.mA[row*136 + xcol8]);
          const float xc = mv*xv + (1.f - mv)*xh;
          if (wcg == cg) NTST(xc, &out[OUT_XCS + ((size_t)b*Tv + t)*XDv + xcol8]);
          L.xcA[row*136 + xcol8] = f2b(xc);
        }
      }
    } else if (wv < 14) {
      const int j = wv - 8, g = j >> 1, hf = j & 1;
      const int ntG = g*32 + cg*2 + hf;
      const int cLoc = hf*16 + l15;
      f4 accG[2] = {{0.f,0.f,0.f,0.f},{0.f,0.f,0.f,0.f}};
      #pragma unroll
      for (int kt = 0; kt < 16; ++kt) {
        s8 b  = FRAG(whhW, (ntG*16 + kt)*64 + ln);
        s8 a0 = *(const s8*)&L.hA[(l15)*520 + kt*32 + l4*8];
        s8 a1 = *(const s8*)&L.hA[(16 + l15)*520 + kt*32 + l4*8];
        accG[0] = MFMA(a0, b, accG[0]);
        accG[1] = MFMA(a1, b, accG[1]);
      }
      #pragma unroll
      for (int rt = 0; rt < 2; ++rt)
        #pragma unroll
        for (int i = 0; i < 4; ++i)
          L.ghS[g*1056 + (rt*16 + l4*4 + i)*33 + cLoc] = accG[rt][i];
    }
    __syncthreads();

    // ---- B3s: z_h + z_c (16 waves, single rt) ----
    {
      const int wrt = wv >> 3;
      f4 acc = {0.f,0.f,0.f,0.f};
      #pragma unroll
      for (int kt = 0; kt < 4; ++kt) {
        s8 a = *(const s8*)&L.xcA[(wrt*16 + l15)*136 + kt*32 + l4*8];
        acc = MFMA(a, FRAG(wfW, (w8*4 + kt)*64 + ln), acc);
      }
      #pragma unroll
      for (int i = 0; i < 4; ++i) {
        const int row = wrt*16 + l4*4 + i;
        const float xv = L.xvS[row*132 + xcol8], mv = b2f(L.mA[row*136 + xcol8]);
        const float zc = mv*xv + (1.f - mv)*(acc[i] + bfR);
        if (wcg == cg) NTST(zc, &out[OUT_ZCS + ((size_t)(r0 + row)*Tv + t)*XDv + xcol8]);
        L.inpA[row*296 + xcol8]       = f2b(zc);
        L.inpA[row*296 + 128 + xcol8] = f2b(mv);
      }
    }
    __syncthreads();

    // ---- B4s: gx on waves 0-11 ----
    if (wv < 12) {
      const int g = wv >> 2, sub = wv & 3;
      const int hf = sub >> 1, rt = sub & 1;
      const int ntG = g*32 + cg*2 + hf;
      const int cLoc = hf*16 + l15;
      f4 acc = {0.f,0.f,0.f,0.f};
      #pragma unroll
      for (int kt = 0; kt < 9; ++kt) {
        s8 a = *(const s8*)&L.inpA[(rt*16 + l15)*296 + kt*32 + l4*8];
        acc = MFMA(a, FRAG(wihW, (ntG*9 + kt)*64 + ln), acc);
      }
      #pragma unroll
      for (int i = 0; i < 4; ++i)
        L.gxS[g*1056 + (rt*16 + l4*4 + i)*33 + cLoc] = acc[i];
    }
    __syncthreads();

    // ---- B5s: GRU (1 cell/thread) -> out + h exchange via sc0|sc1 buffer store ----
    {
      const int row = crow;
      const int b = r0 + row, jc = c0 + cjj;
      const float xr = L.gxS[row*33 + cjj]        + bihR[0];
      const float xz = L.gxS[1056 + row*33 + cjj] + bihR[1];
      const float xn = L.gxS[2112 + row*33 + cjj] + bihR[2];
      const float hr = L.ghS[row*33 + cjj]        + bhhR[0];
      const float hz = L.ghS[1056 + row*33 + cjj] + bhhR[1];
      const float hn = L.ghS[2112 + row*33 + cjj] + bhhR[2];
      const float r = sig_f(xr + hr), z = sig_f(xz + hz);
      const float n = tanh_f(xn + r*hn);
      const float hpv = L.hp32[row*32 + cjj];
      const float hfv = (t < lensG0) ? ((1.f - z)*n + z*hpv) : hpv;
      NTST(hfv, &out[OUT_HS + ((size_t)b*Tv + t)*Hv + jc]);
      if (t == Tv - 1) NTST(hfv, &out[OUT_HN + (size_t)b*Hv + jc]);
      const float partner = __shfl_xor(hfv, 1);
      if ((cjj & 1) == 0) {
        const unsigned int pk = (unsigned int)f2b(hfv) | ((unsigned int)f2b(partner) << 16);
        const int voff = (t & 1)*(1 << 20) + (b*256 + cg*16 + (cjj >> 1))*4;
        __builtin_amdgcn_raw_buffer_store_b32(pk, hsrd, voff, 0, CPOL_SC01);
      }
    }
    rgbar_nf(bar, lgenR, rg);
  }
}

extern "C" void kernel_launch(void* const* d_in, const int* in_sizes, int n_in,
                              void* d_out, int out_size, void* d_ws, size_t ws_size,
                              hipStream_t stream) {
  (void)in_sizes; (void)n_in; (void)out_size; (void)ws_size;
  hipMemsetAsync(d_ws, 0, 8192, stream);
  rits_main<<<NB, NT, 0, stream>>>(
      (const float*)d_in[0],  (const int*)d_in[1],   (const float*)d_in[2],
      (const float*)d_in[3],  (const float*)d_in[4], (const float*)d_in[5],
      (const int*)d_in[6],
      (const float*)d_in[7],  (const float*)d_in[8],
      (const float*)d_in[9],  (const float*)d_in[10],
      (const float*)d_in[11], (const float*)d_in[12],
      (const float*)d_in[13], (const float*)d_in[14],
      (const float*)d_in[15], (const float*)d_in[16],
      (const float*)d_in[17], (const float*)d_in[18],
      (const float*)d_in[19], (const float*)d_in[20],
      (const float*)d_in[21], (const float*)d_in[22],
      (const float*)d_in[23], (const float*)d_in[24],
      (float*)d_out, (float*)d_ws);
}